// Round 10
// baseline (728.202 us; speedup 1.0000x reference)
//
#include <hip/hip_runtime.h>

#define NN 100000
#define NE 3200000
#define NB 391        // coarse buckets: dst>>8, 256 nodes each
#define CAP 9216      // per-bucket pair capacity (mean 8184, sigma~90, +11 sigma)
#define PB 16         // edges per thread in bin part
#define CH_A (256 * PB)
#define BIN_NBLK ((NE + CH_A - 1) / CH_A)   // 782
#define GEMM_NBLK (NN / 32)                 // 3125

typedef _Float16 half4 __attribute__((ext_vector_type(4)));
typedef _Float16 half8 __attribute__((ext_vector_type(8)));

// ---------- helpers ----------
__device__ __forceinline__ float4 f4fma(float s, float4 a, float4 c) {
  c.x = fmaf(s, a.x, c.x); c.y = fmaf(s, a.y, c.y);
  c.z = fmaf(s, a.z, c.z); c.w = fmaf(s, a.w, c.w);
  return c;
}

template<int CTRL>
__device__ __forceinline__ float4 quad_bcast(float4 v) {
  float4 r;
  r.x = __int_as_float(__builtin_amdgcn_update_dpp(__float_as_int(v.x), __float_as_int(v.x), CTRL, 0xF, 0xF, false));
  r.y = __int_as_float(__builtin_amdgcn_update_dpp(__float_as_int(v.y), __float_as_int(v.y), CTRL, 0xF, 0xF, false));
  r.z = __int_as_float(__builtin_amdgcn_update_dpp(__float_as_int(v.z), __float_as_int(v.z), CTRL, 0xF, 0xF, false));
  r.w = __int_as_float(__builtin_amdgcn_update_dpp(__float_as_int(v.w), __float_as_int(v.w), CTRL, 0xF, 0xF, false));
  return r;
}

// ---------- K1: fused bin (blocks 0..781) + gemm1 (blocks 782..3906) ----------
// bin: coarse-bucket edges, coalesced PACKED writes (src|24b + dstlow<<24).
// gemm1: xw1h[n][16] = fp16( x[n][256] @ W1[256][16] ) -- UNSCALED here;
// hist pre-scales xw1h by dinv[n] in place (1 divergent gather/edge in agg1).
__global__ __launch_bounds__(256) void k1_kernel(const int* __restrict__ ei,
                                                 int* __restrict__ bucket_cursor,
                                                 int* __restrict__ pairs,
                                                 const float* __restrict__ x,
                                                 const float* __restrict__ W1,
                                                 _Float16* __restrict__ xw1h) {
  int t = threadIdx.x;
  if (blockIdx.x < BIN_NBLK) {
    // ---------------- bin body (R4-proven, NB=391) ----------------
    __shared__ int  cnt[4][NB];
    __shared__ int  wcur[4][NB];   // per-wave staging cursor (block-local slot)
    __shared__ int  lbase[NB];     // block-local exclusive scan of bucket totals
    __shared__ int  gbase[NB];     // reserved base within bucket region
    __shared__ int  sc[512];
    __shared__ int2 stage[CH_A];   // 32 KB
    __shared__ int  w64flag;
    int wv = t >> 6;
    for (int k = t; k < 4 * NB; k += 256) (&cnt[0][0])[k] = 0;
    if (t < 64) {
      int o = (t < 32) ? ei[2 * t + 1] : 0;
      unsigned long long bl = __ballot(o != 0);
      if (t == 0) w64flag = (bl == 0ULL) ? 1 : 0;
    }
    __syncthreads();
    bool w64 = (w64flag != 0);
    int base = blockIdx.x * CH_A;
    int nval = min(CH_A, NE - base);
    int s[PB], d[PB];
    if (w64) {
      // edge pair e0=base+i*512+2t, e0+1; int64 words {lo,hi,lo,hi} -> int4 .x,.z
#pragma unroll
      for (int i = 0; i < 8; ++i) {
        int e0 = base + i * 512 + 2 * t;
        if (e0 < NE) {  // e0 even, NE even -> e0+1 < NE too
          int4 svv = *(const int4*)(ei + 2 * (size_t)e0);
          int4 dvv = *(const int4*)(ei + 2 * (size_t)NE + 2 * (size_t)e0);
          s[2 * i] = svv.x; s[2 * i + 1] = svv.z;
          d[2 * i] = dvv.x; d[2 * i + 1] = dvv.z;
          atomicAdd(&cnt[wv][dvv.x >> 8], 1);
          atomicAdd(&cnt[wv][dvv.z >> 8], 1);
        } else {
          d[2 * i] = -1; d[2 * i + 1] = -1;
        }
      }
    } else {
#pragma unroll
      for (int i = 0; i < PB; ++i) {
        int e = base + i * 256 + t;
        if (e < NE) {
          s[i] = ei[e];
          d[i] = ei[NE + e];
          atomicAdd(&cnt[wv][d[i] >> 8], 1);
        } else {
          d[i] = -1;
        }
      }
    }
    __syncthreads();
    // block scan over bucket totals (512-wide, 2 per thread)
    int tA = (t < NB) ? cnt[0][t] + cnt[1][t] + cnt[2][t] + cnt[3][t] : 0;
    int tB = (t + 256 < NB) ? cnt[0][t + 256] + cnt[1][t + 256] + cnt[2][t + 256] + cnt[3][t + 256] : 0;
    sc[t] = tA; sc[t + 256] = tB;
    __syncthreads();
#pragma unroll
    for (int off = 1; off < 512; off <<= 1) {
      int u0 = (t >= off) ? sc[t - off] : 0;
      int u1 = (t + 256 >= off) ? sc[t + 256 - off] : 0;
      __syncthreads();
      sc[t] += u0; sc[t + 256] += u1;
      __syncthreads();
    }
#pragma unroll
    for (int h = 0; h < 2; ++h) {
      int k = t + h * 256;
      if (k < NB) {
        int tot = (h == 0) ? tA : tB;
        int lb = sc[k] - tot;
        lbase[k] = lb;
        gbase[k] = (tot > 0) ? atomicAdd(&bucket_cursor[k], tot) : 0;
        int c0 = cnt[0][k], c1 = cnt[1][k], c2 = cnt[2][k];
        wcur[0][k] = lb;
        wcur[1][k] = lb + c0;
        wcur[2][k] = lb + c0 + c1;
        wcur[3][k] = lb + c0 + c1 + c2;
      }
    }
    __syncthreads();
#pragma unroll
    for (int i = 0; i < PB; ++i) {
      if (d[i] >= 0) {
        int b = d[i] >> 8;
        int slot = atomicAdd(&wcur[wv][b], 1);
        stage[slot] = make_int2(s[i], d[i]);
      }
    }
    __syncthreads();
    // coalesced writeout: consecutive k are runs within one bucket; packed 4B
    for (int k = t; k < nval; k += 256) {
      int2 p = stage[k];
      int b = p.y >> 8;
      pairs[(size_t)b * CAP + gbase[b] + (k - lbase[b])] = p.x | ((p.y & 255) << 24);
    }
  } else {
    // ---------------- gemm1 body (8 nodes/wave, unscaled out; R6-proven) ----------------
    const int bid  = blockIdx.x - BIN_NBLK;
    const int lane = t & 63;
    const int wv   = t >> 6;
    const int node0 = (bid * 4 + wv) * 8;
    const int cg_ = lane >> 2;
    const int jl = lane & 3;
    float4 w[16];
#pragma unroll
    for (int k = 0; k < 4; ++k)
#pragma unroll
      for (int c = 0; c < 4; ++c)
        w[k * 4 + c] = *(const float4*)(W1 + (cg_ * 16 + k * 4 + c) * 16 + jl * 4);
    float4 xv[8];
#pragma unroll
    for (int i = 0; i < 8; ++i)
      xv[i] = *(const float4*)(x + (size_t)(node0 + i) * 256 + lane * 4);
    float4 acc[8];
#pragma unroll
    for (int i = 0; i < 8; ++i) acc[i] = make_float4(0.f, 0.f, 0.f, 0.f);
#pragma unroll
    for (int i = 0; i < 8; ++i) {
      float4 b = quad_bcast<0x00>(xv[i]);
      acc[i] = f4fma(b.x, w[0], acc[i]);  acc[i] = f4fma(b.y, w[1], acc[i]);
      acc[i] = f4fma(b.z, w[2], acc[i]);  acc[i] = f4fma(b.w, w[3], acc[i]);
    }
#pragma unroll
    for (int i = 0; i < 8; ++i) {
      float4 b = quad_bcast<0x55>(xv[i]);
      acc[i] = f4fma(b.x, w[4], acc[i]);  acc[i] = f4fma(b.y, w[5], acc[i]);
      acc[i] = f4fma(b.z, w[6], acc[i]);  acc[i] = f4fma(b.w, w[7], acc[i]);
    }
#pragma unroll
    for (int i = 0; i < 8; ++i) {
      float4 b = quad_bcast<0xAA>(xv[i]);
      acc[i] = f4fma(b.x, w[8], acc[i]);  acc[i] = f4fma(b.y, w[9], acc[i]);
      acc[i] = f4fma(b.z, w[10], acc[i]); acc[i] = f4fma(b.w, w[11], acc[i]);
    }
#pragma unroll
    for (int i = 0; i < 8; ++i) {
      float4 b = quad_bcast<0xFF>(xv[i]);
      acc[i] = f4fma(b.x, w[12], acc[i]); acc[i] = f4fma(b.y, w[13], acc[i]);
      acc[i] = f4fma(b.z, w[14], acc[i]); acc[i] = f4fma(b.w, w[15], acc[i]);
    }
#pragma unroll
    for (int m = 4; m <= 32; m <<= 1) {
#pragma unroll
      for (int i = 0; i < 8; ++i) {
        acc[i].x += __shfl_xor(acc[i].x, m);
        acc[i].y += __shfl_xor(acc[i].y, m);
        acc[i].z += __shfl_xor(acc[i].z, m);
        acc[i].w += __shfl_xor(acc[i].w, m);
      }
    }
    if (lane < 4) {
#pragma unroll
      for (int i = 0; i < 8; ++i) {
        float4 a = acc[i];
        half4 hv;
        hv[0] = (_Float16)a.x; hv[1] = (_Float16)a.y;
        hv[2] = (_Float16)a.z; hv[3] = (_Float16)a.w;
        *(half4*)(xw1h + (size_t)(node0 + i) * 16 + lane * 4) = hv;
      }
    }
  }
}

// Per-bucket degree histogram -> dinv, then pre-scale xw1h by dinv IN PLACE.
// 2-edge unrolled loop (2 loads in flight per lane).
__global__ __launch_bounds__(512) void hist_kernel(const int* __restrict__ pairs,
                                                   const int* __restrict__ bucket_cursor,
                                                   float* __restrict__ dinv,
                                                   _Float16* __restrict__ xw1h) {
  __shared__ int hist[2][256];
  __shared__ float dl[256];
  int t = threadIdx.x;
  int b = blockIdx.x;
  int cnt_b = bucket_cursor[b];
  size_t in_base = (size_t)b * CAP;
  if (t < 256) { hist[0][t] = 0; hist[1][t] = 0; }
  __syncthreads();
  int hs = t >> 8;
  for (int i = t; i < cnt_b; i += 1024) {
    int pkA = pairs[in_base + i];
    bool hasB = (i + 512) < cnt_b;
    int pkB = hasB ? pairs[in_base + i + 512] : 0;
    atomicAdd(&hist[hs][((unsigned)pkA) >> 24], 1);
    if (hasB) atomicAdd(&hist[hs][((unsigned)pkB) >> 24], 1);
  }
  __syncthreads();
  if (t < 256) {
    int n = b * 256 + t;
    if (n < NN) {
      float dv = rsqrtf((float)(hist[0][t] + hist[1][t]) + 1.0f);  // +1 self loop
      dinv[n] = dv;
      dl[t] = dv;
    }
  }
  __syncthreads();
  // in-place scale: 2 lanes per node, 16B (half8) each
  {
    int n0 = t >> 1, h = t & 1;
    int n = b * 256 + n0;
    if (n < NN) {
      float dv = dl[n0];
      half8* p8 = (half8*)(xw1h + (size_t)n * 16 + h * 8);
      half8 v = *p8;
#pragma unroll
      for (int f = 0; f < 8; ++f) v[f] = (_Float16)((float)v[f] * dv);
      *p8 = v;
    }
  }
}

// Layer 1 via bucketed LDS scatter-accumulate, PAIR-SPLIT (2 lanes/edge, one
// 16B half each -> one 64B line request per edge). FLOAT accumulators via
// unsafeAtomicAdd -> native fire-and-forget ds_add_f32 (NOT atomicAdd(float*),
// which CAS-loops -- R2 lesson). 2-edge pipeline: 2 gathers in flight/lane.
__global__ __launch_bounds__(1024) void agg1_kernel(const int* __restrict__ pairs,
                                                    const int* __restrict__ bucket_cursor,
                                                    const float* __restrict__ dinv,
                                                    const _Float16* __restrict__ xw1h,
                                                    const float* __restrict__ W2,
                                                    const float* __restrict__ b1,
                                                    _Float16* __restrict__ h1w2h) {
  __shared__ float acc[16][257];   // 16.4 KB
  int t = threadIdx.x;
  int b = blockIdx.x;
  int cnt_b = bucket_cursor[b];
  size_t in_base = (size_t)b * CAP;
  for (int k = t; k < 16 * 257; k += 1024) (&acc[0][0])[k] = 0.f;
  __syncthreads();
  {
    int hh = t & 1;           // feature half
    int i0 = t >> 1;          // edge lane (512 edge-slots)
    for (int i = i0; i < cnt_b; i += 1024) {   // edges i and i+512 per iter
      int pkA = pairs[in_base + i];
      bool hasB = (i + 512) < cnt_b;
      int pkB = hasB ? pairs[in_base + i + 512] : 0;
      int sA = pkA & 0xFFFFFF, nA = ((unsigned)pkA) >> 24;
      half8 vA = *(const half8*)(xw1h + (size_t)sA * 16 + hh * 8);  // pre-scaled
      int sB = pkB & 0xFFFFFF, nB = ((unsigned)pkB) >> 24;
      half8 vB;
      if (hasB) vB = *(const half8*)(xw1h + (size_t)sB * 16 + hh * 8);
#pragma unroll
      for (int f = 0; f < 8; ++f)
        unsafeAtomicAdd(&acc[hh * 8 + f][nA], (float)vA[f]);
      if (hasB) {
#pragma unroll
        for (int f = 0; f < 8; ++f)
          unsafeAtomicAdd(&acc[hh * 8 + f][nB], (float)vB[f]);
      }
    }
  }
  __syncthreads();
  // epilogue: 4 threads per node; sub = feature quarter
  int n0 = t >> 2, sub = t & 3;
  int n = b * 256 + n0;
  if (n < NN) {
    float dn = dinv[n];
    half4 sv = *(const half4*)(xw1h + (size_t)n * 16 + sub * 4);  // pre-scaled
    float4 bv = *(const float4*)(b1 + sub * 4);
    float bb[4] = {bv.x, bv.y, bv.z, bv.w};
    float p[8] = {0.f, 0.f, 0.f, 0.f, 0.f, 0.f, 0.f, 0.f};
    const float4* W2v = (const float4*)W2;
#pragma unroll
    for (int f = 0; f < 4; ++f) {
      int fg = sub * 4 + f;
      // h = relu( dn*(sum_edges dinv[s]*xw1[s] + dinv[n]*xw1[n]) + b1 )
      float h = fmaxf(fmaf(dn, acc[fg][n0] + (float)sv[f], bb[f]), 0.f);
      float4 wlo = W2v[fg * 2];
      float4 whi = W2v[fg * 2 + 1];
      p[0] = fmaf(h, wlo.x, p[0]); p[1] = fmaf(h, wlo.y, p[1]);
      p[2] = fmaf(h, wlo.z, p[2]); p[3] = fmaf(h, wlo.w, p[3]);
      p[4] = fmaf(h, whi.x, p[4]); p[5] = fmaf(h, whi.y, p[5]);
      p[6] = fmaf(h, whi.z, p[6]); p[7] = fmaf(h, whi.w, p[7]);
    }
    // reduce over sub (lane bits 0,1)
#pragma unroll
    for (int m = 1; m <= 2; m <<= 1)
#pragma unroll
      for (int j = 0; j < 8; ++j)
        p[j] += __shfl_xor(p[j], m);
    if (sub == 0) {
      half8 hv;
#pragma unroll
      for (int j = 0; j < 8; ++j) hv[j] = (_Float16)(p[j] * dn);  // scaled by dinv[n]
      *(half8*)(h1w2h + (size_t)n * 8) = hv;
    }
  }
}

// Layer 2: PAIR-SPLIT (2 lanes/edge, 8B half-row each -> one line request per
// edge), float ds_add_f32 accumulators, 2-edge pipeline, + log_softmax(8).
__global__ __launch_bounds__(1024) void agg2_kernel(const int* __restrict__ pairs,
                                                    const int* __restrict__ bucket_cursor,
                                                    const float* __restrict__ dinv,
                                                    const _Float16* __restrict__ h1w2h,
                                                    const float* __restrict__ b2,
                                                    float* __restrict__ out) {
  __shared__ float acc[8][257];   // 8.2 KB
  int t = threadIdx.x;
  int b = blockIdx.x;
  int cnt_b = bucket_cursor[b];
  size_t in_base = (size_t)b * CAP;
  for (int k = t; k < 8 * 257; k += 1024) (&acc[0][0])[k] = 0.f;
  __syncthreads();
  {
    int q = t & 1;            // 4-feature half
    int i0 = t >> 1;          // edge lane (512 edge-slots)
    for (int i = i0; i < cnt_b; i += 1024) {   // edges i and i+512 per iter
      int pkA = pairs[in_base + i];
      bool hasB = (i + 512) < cnt_b;
      int pkB = hasB ? pairs[in_base + i + 512] : 0;
      int sA = pkA & 0xFFFFFF, nA = ((unsigned)pkA) >> 24;
      half4 vA = *(const half4*)(h1w2h + (size_t)sA * 8 + q * 4);  // pre-scaled
      int sB = pkB & 0xFFFFFF, nB = ((unsigned)pkB) >> 24;
      half4 vB;
      if (hasB) vB = *(const half4*)(h1w2h + (size_t)sB * 8 + q * 4);
#pragma unroll
      for (int f = 0; f < 4; ++f)
        unsafeAtomicAdd(&acc[q * 4 + f][nA], (float)vA[f]);
      if (hasB) {
#pragma unroll
        for (int f = 0; f < 4; ++f)
          unsafeAtomicAdd(&acc[q * 4 + f][nB], (float)vB[f]);
      }
    }
  }
  __syncthreads();
  // epilogue: 2 threads per node; q = feature half
  if (t < 512) {
    int n0 = t >> 1, q = t & 1;
    int n = b * 256 + n0;
    if (n < NN) {
      float dn = dinv[n];
      half4 sv = *(const half4*)(h1w2h + (size_t)n * 8 + q * 4);
      float4 bv = *(const float4*)(b2 + q * 4);
      float v0 = fmaf(dn, acc[q * 4 + 0][n0] + (float)sv[0], bv.x);
      float v1 = fmaf(dn, acc[q * 4 + 1][n0] + (float)sv[1], bv.y);
      float v2 = fmaf(dn, acc[q * 4 + 2][n0] + (float)sv[2], bv.z);
      float v3 = fmaf(dn, acc[q * 4 + 3][n0] + (float)sv[3], bv.w);
      float mh = fmaxf(fmaxf(v0, v1), fmaxf(v2, v3));
      float m = fmaxf(mh, __shfl_xor(mh, 1));
      float se = expf(v0 - m) + expf(v1 - m) + expf(v2 - m) + expf(v3 - m);
      float st = se + __shfl_xor(se, 1);
      float ls = m + logf(st);
      *(float4*)(out + (size_t)n * 8 + q * 4) = make_float4(v0 - ls, v1 - ls, v2 - ls, v3 - ls);
    }
  }
}

// ---------- launch ----------
extern "C" void kernel_launch(void* const* d_in, const int* in_sizes, int n_in,
                              void* d_out, int out_size, void* d_ws, size_t ws_size,
                              hipStream_t stream) {
  const float* x  = (const float*)d_in[0];
  const int*   ei = (const int*)d_in[1];
  const float* W1 = (const float*)d_in[2];
  const float* b1 = (const float*)d_in[3];
  const float* W2 = (const float*)d_in[4];
  const float* b2 = (const float*)d_in[5];
  float* out = (float*)d_out;

  // workspace (~20 MB total)
  float*    dinv          = (float*)d_ws;                         // NN floats
  int*      bucket_cursor = (int*)(dinv + NN);                    // NB ints
  int*      pairs         = (int*)dinv + 100400;                  // NB*CAP (16B-aligned)
  _Float16* xw1h  = (_Float16*)(pairs + (size_t)NB * CAP);        // 16N halves (3.2MB)
  _Float16* h1w2h = xw1h + (size_t)16 * NN;                       // 8N halves (1.6MB)

  hipMemsetAsync(bucket_cursor, 0, (size_t)NB * sizeof(int), stream);
  k1_kernel<<<BIN_NBLK + GEMM_NBLK, 256, 0, stream>>>(ei, bucket_cursor, pairs, x, W1, xw1h);
  hist_kernel<<<NB, 512, 0, stream>>>(pairs, bucket_cursor, dinv, xw1h);
  agg1_kernel<<<NB, 1024, 0, stream>>>(pairs, bucket_cursor, dinv, xw1h, W2, b1, h1w2h);
  agg2_kernel<<<NB, 1024, 0, stream>>>(pairs, bucket_cursor, dinv, h1w2h, b2, out);
}

// Round 11
// 267.453 us; speedup vs baseline: 2.7227x; 2.7227x over previous
//
#include <hip/hip_runtime.h>

#define NN 100000
#define NE 3200000
#define NB 391        // coarse buckets: dst>>8, 256 nodes each
#define CAP 9216      // per-bucket pair capacity (mean 8184, sigma~90, +11 sigma)
#define PB 16         // edges per thread in bin part
#define CH_A (256 * PB)
#define BIN_NBLK ((NE + CH_A - 1) / CH_A)   // 782
#define GEMM_NBLK (NN / 32)                 // 3125
#define FXS 65536.0f  // fixed-point scale: int LDS atomics are the only
#define FXI (1.0f / 65536.0f)  // fire-and-forget path (R2/R10: float = CAS loop)

typedef _Float16 half4 __attribute__((ext_vector_type(4)));
typedef _Float16 half8 __attribute__((ext_vector_type(8)));

// ---------- helpers ----------
__device__ __forceinline__ float4 f4fma(float s, float4 a, float4 c) {
  c.x = fmaf(s, a.x, c.x); c.y = fmaf(s, a.y, c.y);
  c.z = fmaf(s, a.z, c.z); c.w = fmaf(s, a.w, c.w);
  return c;
}

template<int CTRL>
__device__ __forceinline__ float4 quad_bcast(float4 v) {
  float4 r;
  r.x = __int_as_float(__builtin_amdgcn_update_dpp(__float_as_int(v.x), __float_as_int(v.x), CTRL, 0xF, 0xF, false));
  r.y = __int_as_float(__builtin_amdgcn_update_dpp(__float_as_int(v.y), __float_as_int(v.y), CTRL, 0xF, 0xF, false));
  r.z = __int_as_float(__builtin_amdgcn_update_dpp(__float_as_int(v.z), __float_as_int(v.z), CTRL, 0xF, 0xF, false));
  r.w = __int_as_float(__builtin_amdgcn_update_dpp(__float_as_int(v.w), __float_as_int(v.w), CTRL, 0xF, 0xF, false));
  return r;
}

// ---------- K1: fused bin (blocks 0..781) + gemm1 (blocks 782..3906) ----------
// bin: coarse-bucket edges, coalesced PACKED writes (src|24b + dstlow<<24).
// gemm1: xw1h[n][16] = fp16( x[n][256] @ W1[256][16] ) -- UNSCALED here;
// hist pre-scales xw1h by dinv[n] in place (1 divergent gather/edge in agg1).
__global__ __launch_bounds__(256) void k1_kernel(const int* __restrict__ ei,
                                                 int* __restrict__ bucket_cursor,
                                                 int* __restrict__ pairs,
                                                 const float* __restrict__ x,
                                                 const float* __restrict__ W1,
                                                 _Float16* __restrict__ xw1h) {
  int t = threadIdx.x;
  if (blockIdx.x < BIN_NBLK) {
    // ---------------- bin body (R4-proven, NB=391) ----------------
    __shared__ int  cnt[4][NB];
    __shared__ int  wcur[4][NB];   // per-wave staging cursor (block-local slot)
    __shared__ int  lbase[NB];     // block-local exclusive scan of bucket totals
    __shared__ int  gbase[NB];     // reserved base within bucket region
    __shared__ int  sc[512];
    __shared__ int2 stage[CH_A];   // 32 KB
    __shared__ int  w64flag;
    int wv = t >> 6;
    for (int k = t; k < 4 * NB; k += 256) (&cnt[0][0])[k] = 0;
    if (t < 64) {
      int o = (t < 32) ? ei[2 * t + 1] : 0;
      unsigned long long bl = __ballot(o != 0);
      if (t == 0) w64flag = (bl == 0ULL) ? 1 : 0;
    }
    __syncthreads();
    bool w64 = (w64flag != 0);
    int base = blockIdx.x * CH_A;
    int nval = min(CH_A, NE - base);
    int s[PB], d[PB];
    if (w64) {
      // edge pair e0=base+i*512+2t, e0+1; int64 words {lo,hi,lo,hi} -> int4 .x,.z
#pragma unroll
      for (int i = 0; i < 8; ++i) {
        int e0 = base + i * 512 + 2 * t;
        if (e0 < NE) {  // e0 even, NE even -> e0+1 < NE too
          int4 svv = *(const int4*)(ei + 2 * (size_t)e0);
          int4 dvv = *(const int4*)(ei + 2 * (size_t)NE + 2 * (size_t)e0);
          s[2 * i] = svv.x; s[2 * i + 1] = svv.z;
          d[2 * i] = dvv.x; d[2 * i + 1] = dvv.z;
          atomicAdd(&cnt[wv][dvv.x >> 8], 1);
          atomicAdd(&cnt[wv][dvv.z >> 8], 1);
        } else {
          d[2 * i] = -1; d[2 * i + 1] = -1;
        }
      }
    } else {
#pragma unroll
      for (int i = 0; i < PB; ++i) {
        int e = base + i * 256 + t;
        if (e < NE) {
          s[i] = ei[e];
          d[i] = ei[NE + e];
          atomicAdd(&cnt[wv][d[i] >> 8], 1);
        } else {
          d[i] = -1;
        }
      }
    }
    __syncthreads();
    // block scan over bucket totals (512-wide, 2 per thread)
    int tA = (t < NB) ? cnt[0][t] + cnt[1][t] + cnt[2][t] + cnt[3][t] : 0;
    int tB = (t + 256 < NB) ? cnt[0][t + 256] + cnt[1][t + 256] + cnt[2][t + 256] + cnt[3][t + 256] : 0;
    sc[t] = tA; sc[t + 256] = tB;
    __syncthreads();
#pragma unroll
    for (int off = 1; off < 512; off <<= 1) {
      int u0 = (t >= off) ? sc[t - off] : 0;
      int u1 = (t + 256 >= off) ? sc[t + 256 - off] : 0;
      __syncthreads();
      sc[t] += u0; sc[t + 256] += u1;
      __syncthreads();
    }
#pragma unroll
    for (int h = 0; h < 2; ++h) {
      int k = t + h * 256;
      if (k < NB) {
        int tot = (h == 0) ? tA : tB;
        int lb = sc[k] - tot;
        lbase[k] = lb;
        gbase[k] = (tot > 0) ? atomicAdd(&bucket_cursor[k], tot) : 0;
        int c0 = cnt[0][k], c1 = cnt[1][k], c2 = cnt[2][k];
        wcur[0][k] = lb;
        wcur[1][k] = lb + c0;
        wcur[2][k] = lb + c0 + c1;
        wcur[3][k] = lb + c0 + c1 + c2;
      }
    }
    __syncthreads();
#pragma unroll
    for (int i = 0; i < PB; ++i) {
      if (d[i] >= 0) {
        int b = d[i] >> 8;
        int slot = atomicAdd(&wcur[wv][b], 1);
        stage[slot] = make_int2(s[i], d[i]);
      }
    }
    __syncthreads();
    // coalesced writeout: consecutive k are runs within one bucket; packed 4B
    for (int k = t; k < nval; k += 256) {
      int2 p = stage[k];
      int b = p.y >> 8;
      pairs[(size_t)b * CAP + gbase[b] + (k - lbase[b])] = p.x | ((p.y & 255) << 24);
    }
  } else {
    // ---------------- gemm1 body (8 nodes/wave, unscaled out; R6-proven) ----------------
    const int bid  = blockIdx.x - BIN_NBLK;
    const int lane = t & 63;
    const int wv   = t >> 6;
    const int node0 = (bid * 4 + wv) * 8;
    const int cg_ = lane >> 2;
    const int jl = lane & 3;
    float4 w[16];
#pragma unroll
    for (int k = 0; k < 4; ++k)
#pragma unroll
      for (int c = 0; c < 4; ++c)
        w[k * 4 + c] = *(const float4*)(W1 + (cg_ * 16 + k * 4 + c) * 16 + jl * 4);
    float4 xv[8];
#pragma unroll
    for (int i = 0; i < 8; ++i)
      xv[i] = *(const float4*)(x + (size_t)(node0 + i) * 256 + lane * 4);
    float4 acc[8];
#pragma unroll
    for (int i = 0; i < 8; ++i) acc[i] = make_float4(0.f, 0.f, 0.f, 0.f);
#pragma unroll
    for (int i = 0; i < 8; ++i) {
      float4 b = quad_bcast<0x00>(xv[i]);
      acc[i] = f4fma(b.x, w[0], acc[i]);  acc[i] = f4fma(b.y, w[1], acc[i]);
      acc[i] = f4fma(b.z, w[2], acc[i]);  acc[i] = f4fma(b.w, w[3], acc[i]);
    }
#pragma unroll
    for (int i = 0; i < 8; ++i) {
      float4 b = quad_bcast<0x55>(xv[i]);
      acc[i] = f4fma(b.x, w[4], acc[i]);  acc[i] = f4fma(b.y, w[5], acc[i]);
      acc[i] = f4fma(b.z, w[6], acc[i]);  acc[i] = f4fma(b.w, w[7], acc[i]);
    }
#pragma unroll
    for (int i = 0; i < 8; ++i) {
      float4 b = quad_bcast<0xAA>(xv[i]);
      acc[i] = f4fma(b.x, w[8], acc[i]);  acc[i] = f4fma(b.y, w[9], acc[i]);
      acc[i] = f4fma(b.z, w[10], acc[i]); acc[i] = f4fma(b.w, w[11], acc[i]);
    }
#pragma unroll
    for (int i = 0; i < 8; ++i) {
      float4 b = quad_bcast<0xFF>(xv[i]);
      acc[i] = f4fma(b.x, w[12], acc[i]); acc[i] = f4fma(b.y, w[13], acc[i]);
      acc[i] = f4fma(b.z, w[14], acc[i]); acc[i] = f4fma(b.w, w[15], acc[i]);
    }
#pragma unroll
    for (int m = 4; m <= 32; m <<= 1) {
#pragma unroll
      for (int i = 0; i < 8; ++i) {
        acc[i].x += __shfl_xor(acc[i].x, m);
        acc[i].y += __shfl_xor(acc[i].y, m);
        acc[i].z += __shfl_xor(acc[i].z, m);
        acc[i].w += __shfl_xor(acc[i].w, m);
      }
    }
    if (lane < 4) {
#pragma unroll
      for (int i = 0; i < 8; ++i) {
        float4 a = acc[i];
        half4 hv;
        hv[0] = (_Float16)a.x; hv[1] = (_Float16)a.y;
        hv[2] = (_Float16)a.z; hv[3] = (_Float16)a.w;
        *(half4*)(xw1h + (size_t)(node0 + i) * 16 + lane * 4) = hv;
      }
    }
  }
}

// Per-bucket degree histogram -> dinv, then pre-scale xw1h by dinv IN PLACE.
// 2-edge unrolled loop (2 loads in flight per lane).
__global__ __launch_bounds__(512) void hist_kernel(const int* __restrict__ pairs,
                                                   const int* __restrict__ bucket_cursor,
                                                   float* __restrict__ dinv,
                                                   _Float16* __restrict__ xw1h) {
  __shared__ int hist[2][256];
  __shared__ float dl[256];
  int t = threadIdx.x;
  int b = blockIdx.x;
  int cnt_b = bucket_cursor[b];
  size_t in_base = (size_t)b * CAP;
  if (t < 256) { hist[0][t] = 0; hist[1][t] = 0; }
  __syncthreads();
  int hs = t >> 8;
  for (int i = t; i < cnt_b; i += 1024) {
    int pkA = pairs[in_base + i];
    bool hasB = (i + 512) < cnt_b;
    int pkB = hasB ? pairs[in_base + i + 512] : 0;
    atomicAdd(&hist[hs][((unsigned)pkA) >> 24], 1);
    if (hasB) atomicAdd(&hist[hs][((unsigned)pkB) >> 24], 1);
  }
  __syncthreads();
  if (t < 256) {
    int n = b * 256 + t;
    if (n < NN) {
      float dv = rsqrtf((float)(hist[0][t] + hist[1][t]) + 1.0f);  // +1 self loop
      dinv[n] = dv;
      dl[t] = dv;
    }
  }
  __syncthreads();
  // in-place scale: 2 lanes per node, 16B (half8) each
  {
    int n0 = t >> 1, h = t & 1;
    int n = b * 256 + n0;
    if (n < NN) {
      float dv = dl[n0];
      half8* p8 = (half8*)(xw1h + (size_t)n * 16 + h * 8);
      half8 v = *p8;
#pragma unroll
      for (int f = 0; f < 8; ++f) v[f] = (_Float16)((float)v[f] * dv);
      *p8 = v;
    }
  }
}

// Layer 1 via bucketed LDS scatter-accumulate, PAIR-SPLIT (2 lanes/edge, one
// 16B half each -> one 64B line request per edge). INT32 fixed-point
// accumulators (native fire-and-forget ds_add_u32 -- float LDS atomics CAS-loop
// on this toolchain, proven R2 AND R10). 2-edge pipeline: 2 gathers in flight.
__global__ __launch_bounds__(1024) void agg1_kernel(const int* __restrict__ pairs,
                                                    const int* __restrict__ bucket_cursor,
                                                    const float* __restrict__ dinv,
                                                    const _Float16* __restrict__ xw1h,
                                                    const float* __restrict__ W2,
                                                    const float* __restrict__ b1,
                                                    _Float16* __restrict__ h1w2h) {
  __shared__ int acc[16][257];   // 16.4 KB
  int t = threadIdx.x;
  int b = blockIdx.x;
  int cnt_b = bucket_cursor[b];
  size_t in_base = (size_t)b * CAP;
  for (int k = t; k < 16 * 257; k += 1024) (&acc[0][0])[k] = 0;
  __syncthreads();
  {
    int hh = t & 1;           // feature half
    int i0 = t >> 1;          // edge lane (512 edge-slots)
    for (int i = i0; i < cnt_b; i += 1024) {   // edges i and i+512 per iter
      int pkA = pairs[in_base + i];
      bool hasB = (i + 512) < cnt_b;
      int pkB = hasB ? pairs[in_base + i + 512] : 0;
      int sA = pkA & 0xFFFFFF, nA = ((unsigned)pkA) >> 24;
      half8 vA = *(const half8*)(xw1h + (size_t)sA * 16 + hh * 8);  // pre-scaled
      int sB = pkB & 0xFFFFFF, nB = ((unsigned)pkB) >> 24;
      half8 vB;
      if (hasB) vB = *(const half8*)(xw1h + (size_t)sB * 16 + hh * 8);
#pragma unroll
      for (int f = 0; f < 8; ++f)
        atomicAdd(&acc[hh * 8 + f][nA], __float2int_rn((float)vA[f] * FXS));
      if (hasB) {
#pragma unroll
        for (int f = 0; f < 8; ++f)
          atomicAdd(&acc[hh * 8 + f][nB], __float2int_rn((float)vB[f] * FXS));
      }
    }
  }
  __syncthreads();
  // epilogue: 4 threads per node; sub = feature quarter
  int n0 = t >> 2, sub = t & 3;
  int n = b * 256 + n0;
  if (n < NN) {
    float dn = dinv[n];
    half4 sv = *(const half4*)(xw1h + (size_t)n * 16 + sub * 4);  // pre-scaled
    float4 bv = *(const float4*)(b1 + sub * 4);
    float bb[4] = {bv.x, bv.y, bv.z, bv.w};
    float p[8] = {0.f, 0.f, 0.f, 0.f, 0.f, 0.f, 0.f, 0.f};
    const float4* W2v = (const float4*)W2;
#pragma unroll
    for (int f = 0; f < 4; ++f) {
      int fg = sub * 4 + f;
      float aggv = (float)acc[fg][n0] * FXI;
      // h = relu( dn*(sum_edges dinv[s]*xw1[s] + dinv[n]*xw1[n]) + b1 )
      float h = fmaxf(fmaf(dn, aggv + (float)sv[f], bb[f]), 0.f);
      float4 wlo = W2v[fg * 2];
      float4 whi = W2v[fg * 2 + 1];
      p[0] = fmaf(h, wlo.x, p[0]); p[1] = fmaf(h, wlo.y, p[1]);
      p[2] = fmaf(h, wlo.z, p[2]); p[3] = fmaf(h, wlo.w, p[3]);
      p[4] = fmaf(h, whi.x, p[4]); p[5] = fmaf(h, whi.y, p[5]);
      p[6] = fmaf(h, whi.z, p[6]); p[7] = fmaf(h, whi.w, p[7]);
    }
    // reduce over sub (lane bits 0,1)
#pragma unroll
    for (int m = 1; m <= 2; m <<= 1)
#pragma unroll
      for (int j = 0; j < 8; ++j)
        p[j] += __shfl_xor(p[j], m);
    if (sub == 0) {
      half8 hv;
#pragma unroll
      for (int j = 0; j < 8; ++j) hv[j] = (_Float16)(p[j] * dn);  // scaled by dinv[n]
      *(half8*)(h1w2h + (size_t)n * 8) = hv;
    }
  }
}

// Layer 2: PAIR-SPLIT (2 lanes/edge, 8B half-row each -> one line request per
// edge), int32 fixed-point accumulators, 2-edge pipeline, + log_softmax(8).
__global__ __launch_bounds__(1024) void agg2_kernel(const int* __restrict__ pairs,
                                                    const int* __restrict__ bucket_cursor,
                                                    const float* __restrict__ dinv,
                                                    const _Float16* __restrict__ h1w2h,
                                                    const float* __restrict__ b2,
                                                    float* __restrict__ out) {
  __shared__ int acc[8][257];   // 8.2 KB
  int t = threadIdx.x;
  int b = blockIdx.x;
  int cnt_b = bucket_cursor[b];
  size_t in_base = (size_t)b * CAP;
  for (int k = t; k < 8 * 257; k += 1024) (&acc[0][0])[k] = 0;
  __syncthreads();
  {
    int q = t & 1;            // 4-feature half
    int i0 = t >> 1;          // edge lane (512 edge-slots)
    for (int i = i0; i < cnt_b; i += 1024) {   // edges i and i+512 per iter
      int pkA = pairs[in_base + i];
      bool hasB = (i + 512) < cnt_b;
      int pkB = hasB ? pairs[in_base + i + 512] : 0;
      int sA = pkA & 0xFFFFFF, nA = ((unsigned)pkA) >> 24;
      half4 vA = *(const half4*)(h1w2h + (size_t)sA * 8 + q * 4);  // pre-scaled
      int sB = pkB & 0xFFFFFF, nB = ((unsigned)pkB) >> 24;
      half4 vB;
      if (hasB) vB = *(const half4*)(h1w2h + (size_t)sB * 8 + q * 4);
#pragma unroll
      for (int f = 0; f < 4; ++f)
        atomicAdd(&acc[q * 4 + f][nA], __float2int_rn((float)vA[f] * FXS));
      if (hasB) {
#pragma unroll
        for (int f = 0; f < 4; ++f)
          atomicAdd(&acc[q * 4 + f][nB], __float2int_rn((float)vB[f] * FXS));
      }
    }
  }
  __syncthreads();
  // epilogue: 2 threads per node; q = feature half
  if (t < 512) {
    int n0 = t >> 1, q = t & 1;
    int n = b * 256 + n0;
    if (n < NN) {
      float dn = dinv[n];
      half4 sv = *(const half4*)(h1w2h + (size_t)n * 8 + q * 4);
      float4 bv = *(const float4*)(b2 + q * 4);
      float v0 = fmaf(dn, (float)acc[q * 4 + 0][n0] * FXI + (float)sv[0], bv.x);
      float v1 = fmaf(dn, (float)acc[q * 4 + 1][n0] * FXI + (float)sv[1], bv.y);
      float v2 = fmaf(dn, (float)acc[q * 4 + 2][n0] * FXI + (float)sv[2], bv.z);
      float v3 = fmaf(dn, (float)acc[q * 4 + 3][n0] * FXI + (float)sv[3], bv.w);
      float mh = fmaxf(fmaxf(v0, v1), fmaxf(v2, v3));
      float m = fmaxf(mh, __shfl_xor(mh, 1));
      float se = expf(v0 - m) + expf(v1 - m) + expf(v2 - m) + expf(v3 - m);
      float st = se + __shfl_xor(se, 1);
      float ls = m + logf(st);
      *(float4*)(out + (size_t)n * 8 + q * 4) = make_float4(v0 - ls, v1 - ls, v2 - ls, v3 - ls);
    }
  }
}

// ---------- launch ----------
extern "C" void kernel_launch(void* const* d_in, const int* in_sizes, int n_in,
                              void* d_out, int out_size, void* d_ws, size_t ws_size,
                              hipStream_t stream) {
  const float* x  = (const float*)d_in[0];
  const int*   ei = (const int*)d_in[1];
  const float* W1 = (const float*)d_in[2];
  const float* b1 = (const float*)d_in[3];
  const float* W2 = (const float*)d_in[4];
  const float* b2 = (const float*)d_in[5];
  float* out = (float*)d_out;

  // workspace (~20 MB total)
  float*    dinv          = (float*)d_ws;                         // NN floats
  int*      bucket_cursor = (int*)(dinv + NN);                    // NB ints
  int*      pairs         = (int*)dinv + 100400;                  // NB*CAP (16B-aligned)
  _Float16* xw1h  = (_Float16*)(pairs + (size_t)NB * CAP);        // 16N halves (3.2MB)
  _Float16* h1w2h = xw1h + (size_t)16 * NN;                       // 8N halves (1.6MB)

  hipMemsetAsync(bucket_cursor, 0, (size_t)NB * sizeof(int), stream);
  k1_kernel<<<BIN_NBLK + GEMM_NBLK, 256, 0, stream>>>(ei, bucket_cursor, pairs, x, W1, xw1h);
  hist_kernel<<<NB, 512, 0, stream>>>(pairs, bucket_cursor, dinv, xw1h);
  agg1_kernel<<<NB, 1024, 0, stream>>>(pairs, bucket_cursor, dinv, xw1h, W2, b1, h1w2h);
  agg2_kernel<<<NB, 1024, 0, stream>>>(pairs, bucket_cursor, dinv, h1w2h, b2, out);
}

// Round 12
// 267.350 us; speedup vs baseline: 2.7238x; 1.0004x over previous
//
#include <hip/hip_runtime.h>

#define NN 100000
#define NE 3200000
#define NB 391        // coarse buckets: dst>>8, 256 nodes each
#define CAP 9216      // per-bucket pair capacity (mean 8184, sigma~90, +11 sigma)
#define PB 16         // edges per thread in bin part
#define CH_A (256 * PB)
#define BIN_NBLK ((NE + CH_A - 1) / CH_A)   // 782
#define GEMM_NBLK (NN / 32)                 // 3125
#define FXS 65536.0f  // fixed-point scale: int LDS atomics are the only
#define FXI (1.0f / 65536.0f)  // fire-and-forget path (R2/R10: float = CAS loop)

typedef _Float16 half4 __attribute__((ext_vector_type(4)));
typedef _Float16 half8 __attribute__((ext_vector_type(8)));

// ---------- helpers ----------
__device__ __forceinline__ float4 f4fma(float s, float4 a, float4 c) {
  c.x = fmaf(s, a.x, c.x); c.y = fmaf(s, a.y, c.y);
  c.z = fmaf(s, a.z, c.z); c.w = fmaf(s, a.w, c.w);
  return c;
}

template<int CTRL>
__device__ __forceinline__ float4 quad_bcast(float4 v) {
  float4 r;
  r.x = __int_as_float(__builtin_amdgcn_update_dpp(__float_as_int(v.x), __float_as_int(v.x), CTRL, 0xF, 0xF, false));
  r.y = __int_as_float(__builtin_amdgcn_update_dpp(__float_as_int(v.y), __float_as_int(v.y), CTRL, 0xF, 0xF, false));
  r.z = __int_as_float(__builtin_amdgcn_update_dpp(__float_as_int(v.z), __float_as_int(v.z), CTRL, 0xF, 0xF, false));
  r.w = __int_as_float(__builtin_amdgcn_update_dpp(__float_as_int(v.w), __float_as_int(v.w), CTRL, 0xF, 0xF, false));
  return r;
}

// ---------- K1: ROLE-INTERLEAVED bin + gemm1 ----------
// bid % 5 == 0 -> bin block (782 of 3907); else gemm (3125). R11 counters
// showed the sequential layout ran pure-bin (latency-bound, VALU 3%) then
// pure-gemm (VALU-bound): 82us = 55+30. Interleaving co-resides ~1 bin block
// (50.7KB LDS, stalled on memory/barriers) with ~4 gemm blocks (0 LDS,
// VALU-hungry) per CU so gemm fills bin's idle issue slots.
__global__ __launch_bounds__(256) void k1_kernel(const int* __restrict__ ei,
                                                 int* __restrict__ bucket_cursor,
                                                 int* __restrict__ pairs,
                                                 const float* __restrict__ x,
                                                 const float* __restrict__ W1,
                                                 _Float16* __restrict__ xw1h) {
  int t = threadIdx.x;
  int bid = blockIdx.x;
  if (bid % 5 == 0) {
    // ---------------- bin body (R4-proven, NB=391) ----------------
    int bin_bid = bid / 5;          // 0..781
    __shared__ int  cnt[4][NB];
    __shared__ int  wcur[4][NB];   // per-wave staging cursor (block-local slot)
    __shared__ int  lbase[NB];     // block-local exclusive scan of bucket totals
    __shared__ int  gbase[NB];     // reserved base within bucket region
    __shared__ int  sc[512];
    __shared__ int2 stage[CH_A];   // 32 KB
    __shared__ int  w64flag;
    int wv = t >> 6;
    for (int k = t; k < 4 * NB; k += 256) (&cnt[0][0])[k] = 0;
    if (t < 64) {
      int o = (t < 32) ? ei[2 * t + 1] : 0;
      unsigned long long bl = __ballot(o != 0);
      if (t == 0) w64flag = (bl == 0ULL) ? 1 : 0;
    }
    __syncthreads();
    bool w64 = (w64flag != 0);
    int base = bin_bid * CH_A;
    int nval = min(CH_A, NE - base);
    int s[PB], d[PB];
    if (w64) {
      // edge pair e0=base+i*512+2t, e0+1; int64 words {lo,hi,lo,hi} -> int4 .x,.z
#pragma unroll
      for (int i = 0; i < 8; ++i) {
        int e0 = base + i * 512 + 2 * t;
        if (e0 < NE) {  // e0 even, NE even -> e0+1 < NE too
          int4 svv = *(const int4*)(ei + 2 * (size_t)e0);
          int4 dvv = *(const int4*)(ei + 2 * (size_t)NE + 2 * (size_t)e0);
          s[2 * i] = svv.x; s[2 * i + 1] = svv.z;
          d[2 * i] = dvv.x; d[2 * i + 1] = dvv.z;
          atomicAdd(&cnt[wv][dvv.x >> 8], 1);
          atomicAdd(&cnt[wv][dvv.z >> 8], 1);
        } else {
          d[2 * i] = -1; d[2 * i + 1] = -1;
        }
      }
    } else {
#pragma unroll
      for (int i = 0; i < PB; ++i) {
        int e = base + i * 256 + t;
        if (e < NE) {
          s[i] = ei[e];
          d[i] = ei[NE + e];
          atomicAdd(&cnt[wv][d[i] >> 8], 1);
        } else {
          d[i] = -1;
        }
      }
    }
    __syncthreads();
    // block scan over bucket totals (512-wide, 2 per thread)
    int tA = (t < NB) ? cnt[0][t] + cnt[1][t] + cnt[2][t] + cnt[3][t] : 0;
    int tB = (t + 256 < NB) ? cnt[0][t + 256] + cnt[1][t + 256] + cnt[2][t + 256] + cnt[3][t + 256] : 0;
    sc[t] = tA; sc[t + 256] = tB;
    __syncthreads();
#pragma unroll
    for (int off = 1; off < 512; off <<= 1) {
      int u0 = (t >= off) ? sc[t - off] : 0;
      int u1 = (t + 256 >= off) ? sc[t + 256 - off] : 0;
      __syncthreads();
      sc[t] += u0; sc[t + 256] += u1;
      __syncthreads();
    }
#pragma unroll
    for (int h = 0; h < 2; ++h) {
      int k = t + h * 256;
      if (k < NB) {
        int tot = (h == 0) ? tA : tB;
        int lb = sc[k] - tot;
        lbase[k] = lb;
        gbase[k] = (tot > 0) ? atomicAdd(&bucket_cursor[k], tot) : 0;
        int c0 = cnt[0][k], c1 = cnt[1][k], c2 = cnt[2][k];
        wcur[0][k] = lb;
        wcur[1][k] = lb + c0;
        wcur[2][k] = lb + c0 + c1;
        wcur[3][k] = lb + c0 + c1 + c2;
      }
    }
    __syncthreads();
#pragma unroll
    for (int i = 0; i < PB; ++i) {
      if (d[i] >= 0) {
        int b = d[i] >> 8;
        int slot = atomicAdd(&wcur[wv][b], 1);
        stage[slot] = make_int2(s[i], d[i]);
      }
    }
    __syncthreads();
    // coalesced writeout: consecutive k are runs within one bucket; packed 4B
    for (int k = t; k < nval; k += 256) {
      int2 p = stage[k];
      int b = p.y >> 8;
      pairs[(size_t)b * CAP + gbase[b] + (k - lbase[b])] = p.x | ((p.y & 255) << 24);
    }
  } else {
    // ---------------- gemm1 body (8 nodes/wave, unscaled out; R6-proven) ----------------
    const int gid  = bid - bid / 5 - 1;   // 0..3124 (gemm blocks among bid%5!=0)
    const int lane = t & 63;
    const int wv   = t >> 6;
    const int node0 = (gid * 4 + wv) * 8;
    const int cg_ = lane >> 2;
    const int jl = lane & 3;
    float4 w[16];
#pragma unroll
    for (int k = 0; k < 4; ++k)
#pragma unroll
      for (int c = 0; c < 4; ++c)
        w[k * 4 + c] = *(const float4*)(W1 + (cg_ * 16 + k * 4 + c) * 16 + jl * 4);
    float4 xv[8];
#pragma unroll
    for (int i = 0; i < 8; ++i)
      xv[i] = *(const float4*)(x + (size_t)(node0 + i) * 256 + lane * 4);
    float4 acc[8];
#pragma unroll
    for (int i = 0; i < 8; ++i) acc[i] = make_float4(0.f, 0.f, 0.f, 0.f);
#pragma unroll
    for (int i = 0; i < 8; ++i) {
      float4 b = quad_bcast<0x00>(xv[i]);
      acc[i] = f4fma(b.x, w[0], acc[i]);  acc[i] = f4fma(b.y, w[1], acc[i]);
      acc[i] = f4fma(b.z, w[2], acc[i]);  acc[i] = f4fma(b.w, w[3], acc[i]);
    }
#pragma unroll
    for (int i = 0; i < 8; ++i) {
      float4 b = quad_bcast<0x55>(xv[i]);
      acc[i] = f4fma(b.x, w[4], acc[i]);  acc[i] = f4fma(b.y, w[5], acc[i]);
      acc[i] = f4fma(b.z, w[6], acc[i]);  acc[i] = f4fma(b.w, w[7], acc[i]);
    }
#pragma unroll
    for (int i = 0; i < 8; ++i) {
      float4 b = quad_bcast<0xAA>(xv[i]);
      acc[i] = f4fma(b.x, w[8], acc[i]);  acc[i] = f4fma(b.y, w[9], acc[i]);
      acc[i] = f4fma(b.z, w[10], acc[i]); acc[i] = f4fma(b.w, w[11], acc[i]);
    }
#pragma unroll
    for (int i = 0; i < 8; ++i) {
      float4 b = quad_bcast<0xFF>(xv[i]);
      acc[i] = f4fma(b.x, w[12], acc[i]); acc[i] = f4fma(b.y, w[13], acc[i]);
      acc[i] = f4fma(b.z, w[14], acc[i]); acc[i] = f4fma(b.w, w[15], acc[i]);
    }
#pragma unroll
    for (int m = 4; m <= 32; m <<= 1) {
#pragma unroll
      for (int i = 0; i < 8; ++i) {
        acc[i].x += __shfl_xor(acc[i].x, m);
        acc[i].y += __shfl_xor(acc[i].y, m);
        acc[i].z += __shfl_xor(acc[i].z, m);
        acc[i].w += __shfl_xor(acc[i].w, m);
      }
    }
    if (lane < 4) {
#pragma unroll
      for (int i = 0; i < 8; ++i) {
        float4 a = acc[i];
        half4 hv;
        hv[0] = (_Float16)a.x; hv[1] = (_Float16)a.y;
        hv[2] = (_Float16)a.z; hv[3] = (_Float16)a.w;
        *(half4*)(xw1h + (size_t)(node0 + i) * 16 + lane * 4) = hv;
      }
    }
  }
}

// Per-bucket degree histogram -> dinv, then pre-scale xw1h by dinv IN PLACE.
// 2-edge unrolled loop (2 loads in flight per lane).
__global__ __launch_bounds__(512) void hist_kernel(const int* __restrict__ pairs,
                                                   const int* __restrict__ bucket_cursor,
                                                   float* __restrict__ dinv,
                                                   _Float16* __restrict__ xw1h) {
  __shared__ int hist[2][256];
  __shared__ float dl[256];
  int t = threadIdx.x;
  int b = blockIdx.x;
  int cnt_b = bucket_cursor[b];
  size_t in_base = (size_t)b * CAP;
  if (t < 256) { hist[0][t] = 0; hist[1][t] = 0; }
  __syncthreads();
  int hs = t >> 8;
  for (int i = t; i < cnt_b; i += 1024) {
    int pkA = pairs[in_base + i];
    bool hasB = (i + 512) < cnt_b;
    int pkB = hasB ? pairs[in_base + i + 512] : 0;
    atomicAdd(&hist[hs][((unsigned)pkA) >> 24], 1);
    if (hasB) atomicAdd(&hist[hs][((unsigned)pkB) >> 24], 1);
  }
  __syncthreads();
  if (t < 256) {
    int n = b * 256 + t;
    if (n < NN) {
      float dv = rsqrtf((float)(hist[0][t] + hist[1][t]) + 1.0f);  // +1 self loop
      dinv[n] = dv;
      dl[t] = dv;
    }
  }
  __syncthreads();
  // in-place scale: 2 lanes per node, 16B (half8) each
  {
    int n0 = t >> 1, h = t & 1;
    int n = b * 256 + n0;
    if (n < NN) {
      float dv = dl[n0];
      half8* p8 = (half8*)(xw1h + (size_t)n * 16 + h * 8);
      half8 v = *p8;
#pragma unroll
      for (int f = 0; f < 8; ++f) v[f] = (_Float16)((float)v[f] * dv);
      *p8 = v;
    }
  }
}

// Layer 1 via bucketed LDS scatter-accumulate, PAIR-SPLIT (2 lanes/edge, one
// 16B half each -> one 64B line request per edge). INT32 fixed-point
// accumulators (native fire-and-forget ds_add_u32 -- float LDS atomics CAS-loop
// on this toolchain, proven R2 AND R10). 2-edge pipeline: 2 gathers in flight.
__global__ __launch_bounds__(1024) void agg1_kernel(const int* __restrict__ pairs,
                                                    const int* __restrict__ bucket_cursor,
                                                    const float* __restrict__ dinv,
                                                    const _Float16* __restrict__ xw1h,
                                                    const float* __restrict__ W2,
                                                    const float* __restrict__ b1,
                                                    _Float16* __restrict__ h1w2h) {
  __shared__ int acc[16][257];   // 16.4 KB
  int t = threadIdx.x;
  int b = blockIdx.x;
  int cnt_b = bucket_cursor[b];
  size_t in_base = (size_t)b * CAP;
  for (int k = t; k < 16 * 257; k += 1024) (&acc[0][0])[k] = 0;
  __syncthreads();
  {
    int hh = t & 1;           // feature half
    int i0 = t >> 1;          // edge lane (512 edge-slots)
    for (int i = i0; i < cnt_b; i += 1024) {   // edges i and i+512 per iter
      int pkA = pairs[in_base + i];
      bool hasB = (i + 512) < cnt_b;
      int pkB = hasB ? pairs[in_base + i + 512] : 0;
      int sA = pkA & 0xFFFFFF, nA = ((unsigned)pkA) >> 24;
      half8 vA = *(const half8*)(xw1h + (size_t)sA * 16 + hh * 8);  // pre-scaled
      int sB = pkB & 0xFFFFFF, nB = ((unsigned)pkB) >> 24;
      half8 vB;
      if (hasB) vB = *(const half8*)(xw1h + (size_t)sB * 16 + hh * 8);
#pragma unroll
      for (int f = 0; f < 8; ++f)
        atomicAdd(&acc[hh * 8 + f][nA], __float2int_rn((float)vA[f] * FXS));
      if (hasB) {
#pragma unroll
        for (int f = 0; f < 8; ++f)
          atomicAdd(&acc[hh * 8 + f][nB], __float2int_rn((float)vB[f] * FXS));
      }
    }
  }
  __syncthreads();
  // epilogue: 4 threads per node; sub = feature quarter
  int n0 = t >> 2, sub = t & 3;
  int n = b * 256 + n0;
  if (n < NN) {
    float dn = dinv[n];
    half4 sv = *(const half4*)(xw1h + (size_t)n * 16 + sub * 4);  // pre-scaled
    float4 bv = *(const float4*)(b1 + sub * 4);
    float bb[4] = {bv.x, bv.y, bv.z, bv.w};
    float p[8] = {0.f, 0.f, 0.f, 0.f, 0.f, 0.f, 0.f, 0.f};
    const float4* W2v = (const float4*)W2;
#pragma unroll
    for (int f = 0; f < 4; ++f) {
      int fg = sub * 4 + f;
      float aggv = (float)acc[fg][n0] * FXI;
      // h = relu( dn*(sum_edges dinv[s]*xw1[s] + dinv[n]*xw1[n]) + b1 )
      float h = fmaxf(fmaf(dn, aggv + (float)sv[f], bb[f]), 0.f);
      float4 wlo = W2v[fg * 2];
      float4 whi = W2v[fg * 2 + 1];
      p[0] = fmaf(h, wlo.x, p[0]); p[1] = fmaf(h, wlo.y, p[1]);
      p[2] = fmaf(h, wlo.z, p[2]); p[3] = fmaf(h, wlo.w, p[3]);
      p[4] = fmaf(h, whi.x, p[4]); p[5] = fmaf(h, whi.y, p[5]);
      p[6] = fmaf(h, whi.z, p[6]); p[7] = fmaf(h, whi.w, p[7]);
    }
    // reduce over sub (lane bits 0,1)
#pragma unroll
    for (int m = 1; m <= 2; m <<= 1)
#pragma unroll
      for (int j = 0; j < 8; ++j)
        p[j] += __shfl_xor(p[j], m);
    if (sub == 0) {
      half8 hv;
#pragma unroll
      for (int j = 0; j < 8; ++j) hv[j] = (_Float16)(p[j] * dn);  // scaled by dinv[n]
      *(half8*)(h1w2h + (size_t)n * 8) = hv;
    }
  }
}

// Layer 2: PAIR-SPLIT (2 lanes/edge, 8B half-row each -> one line request per
// edge), int32 fixed-point accumulators, 2-edge pipeline, + log_softmax(8).
__global__ __launch_bounds__(1024) void agg2_kernel(const int* __restrict__ pairs,
                                                    const int* __restrict__ bucket_cursor,
                                                    const float* __restrict__ dinv,
                                                    const _Float16* __restrict__ h1w2h,
                                                    const float* __restrict__ b2,
                                                    float* __restrict__ out) {
  __shared__ int acc[8][257];   // 8.2 KB
  int t = threadIdx.x;
  int b = blockIdx.x;
  int cnt_b = bucket_cursor[b];
  size_t in_base = (size_t)b * CAP;
  for (int k = t; k < 8 * 257; k += 1024) (&acc[0][0])[k] = 0;
  __syncthreads();
  {
    int q = t & 1;            // 4-feature half
    int i0 = t >> 1;          // edge lane (512 edge-slots)
    for (int i = i0; i < cnt_b; i += 1024) {   // edges i and i+512 per iter
      int pkA = pairs[in_base + i];
      bool hasB = (i + 512) < cnt_b;
      int pkB = hasB ? pairs[in_base + i + 512] : 0;
      int sA = pkA & 0xFFFFFF, nA = ((unsigned)pkA) >> 24;
      half4 vA = *(const half4*)(h1w2h + (size_t)sA * 8 + q * 4);  // pre-scaled
      int sB = pkB & 0xFFFFFF, nB = ((unsigned)pkB) >> 24;
      half4 vB;
      if (hasB) vB = *(const half4*)(h1w2h + (size_t)sB * 8 + q * 4);
#pragma unroll
      for (int f = 0; f < 4; ++f)
        atomicAdd(&acc[q * 4 + f][nA], __float2int_rn((float)vA[f] * FXS));
      if (hasB) {
#pragma unroll
        for (int f = 0; f < 4; ++f)
          atomicAdd(&acc[q * 4 + f][nB], __float2int_rn((float)vB[f] * FXS));
      }
    }
  }
  __syncthreads();
  // epilogue: 2 threads per node; q = feature half
  if (t < 512) {
    int n0 = t >> 1, q = t & 1;
    int n = b * 256 + n0;
    if (n < NN) {
      float dn = dinv[n];
      half4 sv = *(const half4*)(h1w2h + (size_t)n * 8 + q * 4);
      float4 bv = *(const float4*)(b2 + q * 4);
      float v0 = fmaf(dn, (float)acc[q * 4 + 0][n0] * FXI + (float)sv[0], bv.x);
      float v1 = fmaf(dn, (float)acc[q * 4 + 1][n0] * FXI + (float)sv[1], bv.y);
      float v2 = fmaf(dn, (float)acc[q * 4 + 2][n0] * FXI + (float)sv[2], bv.z);
      float v3 = fmaf(dn, (float)acc[q * 4 + 3][n0] * FXI + (float)sv[3], bv.w);
      float mh = fmaxf(fmaxf(v0, v1), fmaxf(v2, v3));
      float m = fmaxf(mh, __shfl_xor(mh, 1));
      float se = expf(v0 - m) + expf(v1 - m) + expf(v2 - m) + expf(v3 - m);
      float st = se + __shfl_xor(se, 1);
      float ls = m + logf(st);
      *(float4*)(out + (size_t)n * 8 + q * 4) = make_float4(v0 - ls, v1 - ls, v2 - ls, v3 - ls);
    }
  }
}

// ---------- launch ----------
extern "C" void kernel_launch(void* const* d_in, const int* in_sizes, int n_in,
                              void* d_out, int out_size, void* d_ws, size_t ws_size,
                              hipStream_t stream) {
  const float* x  = (const float*)d_in[0];
  const int*   ei = (const int*)d_in[1];
  const float* W1 = (const float*)d_in[2];
  const float* b1 = (const float*)d_in[3];
  const float* W2 = (const float*)d_in[4];
  const float* b2 = (const float*)d_in[5];
  float* out = (float*)d_out;

  // workspace (~20 MB total)
  float*    dinv          = (float*)d_ws;                         // NN floats
  int*      bucket_cursor = (int*)(dinv + NN);                    // NB ints
  int*      pairs         = (int*)dinv + 100400;                  // NB*CAP (16B-aligned)
  _Float16* xw1h  = (_Float16*)(pairs + (size_t)NB * CAP);        // 16N halves (3.2MB)
  _Float16* h1w2h = xw1h + (size_t)16 * NN;                       // 8N halves (1.6MB)

  hipMemsetAsync(bucket_cursor, 0, (size_t)NB * sizeof(int), stream);
  k1_kernel<<<BIN_NBLK + GEMM_NBLK, 256, 0, stream>>>(ei, bucket_cursor, pairs, x, W1, xw1h);
  hist_kernel<<<NB, 512, 0, stream>>>(pairs, bucket_cursor, dinv, xw1h);
  agg1_kernel<<<NB, 1024, 0, stream>>>(pairs, bucket_cursor, dinv, xw1h, W2, b1, h1w2h);
  agg2_kernel<<<NB, 1024, 0, stream>>>(pairs, bucket_cursor, dinv, h1w2h, b2, out);
}